// Round 2
// baseline (192.200 us; speedup 1.0000x reference)
//
#include <hip/hip_runtime.h>

#define N_NODES 50000
#define IN_CH   128
#define OUT_CH  64
#define N_EDGES 800000
#define NBINS   49      // bin = t >> 10
#define LBCAP   128     // per-(block,bin) LDS cap; Poisson(32.7), P(>128)~0
#define BINCAP  20000   // per-bin global cap; mean 16.3K, sd 128
#define PCAP    64      // esrc planes; deg Poisson(16), P(>64)~1e-18
#define WT_STR  136     // bf16 per WT row
#define SA_B    500     // scatter_a blocks (2/CU); 500*1600 = 800000 exactly
#define SA_E    1600
#define SB_B    49      // scatter_b blocks (single-writer per bin)
#define GEMM_BL 196     // gemm blocks in fused K2; 196*16 waves >= 3125 tiles
#define HOP_HB  12500   // hop blocks per channel-half (4 nodes/block)
#define ZPL     (N_NODES * 4)   // uint4 per z plane (half-channels, 64B/node)

// NOTE (R9): ~92us of dur_us is harness 256MB ws poison fills. Budget = dur-92.
// NOTE (R1): integer inputs arrive as int32.
// NOTE (R12-R14): random fine-grain global stores -> ~50MB partial-line traffic;
// two-phase binning fixes writes (R13: 4.2MB) BUT the phases must (a) run at
// >=2 blocks/CU, (b) not serialize bin copies, (c) overlap the gemm in the same
// dispatch (R10-R12 got the gemm for free under the scatter; R14 paid serially).
// NOTE (R15): hops were ~2x25us at ~4.7TB/s effective -- gathers missed the
// 4MiB/XCD L2 (z = 6.4MB interleaved). Split each hop into two half-channel
// passes over PLANAR z (two 3.2MB planes) so the active plane is L2-resident;
// nontemporal z1/out stores keep the streaming writes from evicting it;
// bijective XCD-chunk swizzle (within each half) shares esrc lines per XCD.
// NOTE (R16): __builtin_nontemporal_store needs ext_vector types, not
// HIP_vector_type structs (uint4/float4) -- use uint4v/float4v.

using short8  = __attribute__((ext_vector_type(8))) short;
using float4v = __attribute__((ext_vector_type(4))) float;
using uint4v  = __attribute__((ext_vector_type(4))) unsigned int;

__device__ __forceinline__ unsigned int bpack(float a, float b) {
    unsigned int ua = __float_as_uint(a), ub = __float_as_uint(b);
    unsigned int ra = (ua + 0x7fffu + ((ua >> 16) & 1u)) >> 16;
    unsigned int rb = (ub + 0x7fffu + ((ub >> 16) & 1u)) & 0xffff0000u;
    return (ra & 0xffffu) | rb;
}

// =================== K1: scatter phase A — bin edges, dense append ===================
__global__ __launch_bounds__(256) void scatter_a(const int* __restrict__ row,
        const int* __restrict__ col, unsigned int* __restrict__ binbuf,
        int* __restrict__ gcur) {
    __shared__ unsigned int sbuf[NBINS][LBCAP];   // 25 KB
    __shared__ int scnt[NBINS];
    __shared__ int sdst[NBINS];
    const int tid = threadIdx.x;
    if (tid < NBINS) scnt[tid] = 0;
    __syncthreads();
    const int e0 = blockIdx.x * SA_E;
    for (int i = tid; i < SA_E / 4; i += 256) {      // 400 int4 per block
        int e = e0 + i * 4;
        int4 t4 = *(const int4*)&col[e];
        int4 s4 = *(const int4*)&row[e];
        const int ts[4] = { t4.x, t4.y, t4.z, t4.w };
        const int ss[4] = { s4.x, s4.y, s4.z, s4.w };
        #pragma unroll
        for (int j = 0; j < 4; ++j) {
            int b = ts[j] >> 10;
            int pos = atomicAdd(&scnt[b], 1);        // LDS atomic
            if (pos < LBCAP)
                sbuf[b][pos] = ((unsigned)(ts[j] & 1023) << 16) | (unsigned)ss[j];
        }
    }
    __syncthreads();
    if (tid < NBINS) {
        int c = scnt[tid]; if (c > LBCAP) c = LBCAP; scnt[tid] = c;
        sdst[tid] = atomicAdd(&gcur[tid], c);        // 1 global atomic/bin
    }
    __syncthreads();
    const int wave = tid >> 6, lane = tid & 63;
    for (int b = wave; b < NBINS; b += 4) {          // wave-parallel dense copy
        int c = scnt[b];
        size_t d = (size_t)b * BINCAP + sdst[b];
        for (int i = lane; i < c; i += 64)
            binbuf[d + i] = sbuf[b][i];
    }
}

// =================== K2 (fused): scatter_b (blocks [0,49)) || MFMA gemm ===================
__global__ __launch_bounds__(1024) void scatb_gemm(
        const unsigned int* __restrict__ binbuf, const int* __restrict__ gcur,
        unsigned short* __restrict__ esrc, unsigned char* __restrict__ fill8,
        const float* __restrict__ x, const float* __restrict__ W,
        float* __restrict__ y) {
    const int bid = blockIdx.x, tid = threadIdx.x;
    if (bid < SB_B) {   // ---- scatter_b ----
        __shared__ int lcnt[1024];
        const int t0 = bid << 10;
        lcnt[tid] = 0;
        __syncthreads();
        int cnt = gcur[bid]; if (cnt > BINCAP) cnt = BINCAP;
        const unsigned int* src = binbuf + (size_t)bid * BINCAP;
        for (int i = tid; i < cnt; i += 1024) {
            unsigned int e = src[i];                 // dense read
            int tl = e >> 16;
            int pos = atomicAdd(&lcnt[tl], 1);       // LDS atomic
            int t = t0 + tl;
            if (pos < PCAP && t < N_NODES)
                esrc[(size_t)pos * N_NODES + t] = (unsigned short)(e & 0xffffu);
        }
        __syncthreads();
        int t = t0 + tid;
        if (t < N_NODES) {
            int v = lcnt[tid]; if (v > PCAP) v = PCAP;
            fill8[t] = (unsigned char)v;
        }
        return;
    }
    // ---- gemm ----
    __shared__ unsigned short sWT[64 * WT_STR];      // 17.4 KB, bf16 WT[c][k]
    for (int i = tid; i < IN_CH * OUT_CH; i += 1024) {
        int k = i >> 6, c = i & 63;
        unsigned int u = __float_as_uint(W[i]);
        u = (u + 0x7fffu + ((u >> 16) & 1u)) >> 16;  // RNE to bf16
        sWT[c * WT_STR + k] = (unsigned short)u;
    }
    __syncthreads();
    const int lane = tid & 63;
    const int quad = lane >> 4;
    const int c15  = lane & 15;
    const int tile = (bid - SB_B) * 16 + (tid >> 6); // one tile per wave
    if (tile >= N_NODES / 16) return;                // after the only barrier

    short8 bf[4][4];
    #pragma unroll
    for (int t = 0; t < 4; ++t)
        #pragma unroll
        for (int ch = 0; ch < 4; ++ch)
            bf[ch][t] = *(const short8*)&sWT[(t * 16 + c15) * WT_STR + ch * 32 + quad * 8];

    const float* xr = x + ((size_t)tile * 16 + c15) * IN_CH;
    float4v acc[4] = {{0.f,0.f,0.f,0.f},{0.f,0.f,0.f,0.f},
                      {0.f,0.f,0.f,0.f},{0.f,0.f,0.f,0.f}};
    #pragma unroll
    for (int ch = 0; ch < 4; ++ch) {
        float4 f0 = *(const float4*)(xr + ch * 32 + quad * 8);
        float4 f1 = *(const float4*)(xr + ch * 32 + quad * 8 + 4);
        unsigned int d0 = bpack(f0.x, f0.y), d1 = bpack(f0.z, f0.w);
        unsigned int d2 = bpack(f1.x, f1.y), d3 = bpack(f1.z, f1.w);
        short8 a8;
        a8[0] = (short)d0; a8[1] = (short)(d0 >> 16);
        a8[2] = (short)d1; a8[3] = (short)(d1 >> 16);
        a8[4] = (short)d2; a8[5] = (short)(d2 >> 16);
        a8[6] = (short)d3; a8[7] = (short)(d3 >> 16);
        #pragma unroll
        for (int t = 0; t < 4; ++t)
            acc[t] = __builtin_amdgcn_mfma_f32_16x16x32_bf16(a8, bf[ch][t], acc[t], 0, 0, 0);
    }
    #pragma unroll
    for (int t = 0; t < 4; ++t)
        #pragma unroll
        for (int r = 0; r < 4; ++r)
            y[((size_t)tile * 16 + quad * 4 + r) * OUT_CH + t * 16 + c15] = acc[t][r];
}

// =================== K3: z0 = D^-1/2 y (fp32 -> bf16, PLANAR halves) ===================
__global__ __launch_bounds__(256) void scale_z0(const float* __restrict__ y,
        const unsigned char* __restrict__ fill8, uint4v* __restrict__ z0) {
    int gid = blockIdx.x * 256 + threadIdx.x;
    if (gid >= N_NODES * 8) return;
    int n = gid >> 3, q = gid & 7;
    int half = q >> 2, qq = q & 3;
    float d = rsqrtf((float)((int)fill8[n] + 1));
    float4 a = ((const float4*)y)[n * 16 + q * 2];
    float4 b = ((const float4*)y)[n * 16 + q * 2 + 1];
    uint4v pk;
    pk.x = bpack(d * a.x, d * a.y);
    pk.y = bpack(d * a.z, d * a.w);
    pk.z = bpack(d * b.x, d * b.y);
    pk.w = bpack(d * b.z, d * b.w);
    z0[(size_t)half * ZPL + n * 4 + qq] = pk;
}

// =================== K4/K5: unweighted (A+I) gather, half-channel passes ===================
// Blocks [0, HOP_HB) = channel half 0 (plane A); [HOP_HB, 2*HOP_HB) = half 1.
// Each plane is 3.2MB -> L2-resident per XCD. 16 groups x 4 lanes x 16B = 64B row.
__global__ __launch_bounds__(256) void hop_gather(const uint4v* __restrict__ hin,
        void* __restrict__ hout, const unsigned char* __restrict__ fill8,
        const unsigned short* __restrict__ esrc, const float* __restrict__ bias,
        int last) {
    int b = blockIdx.x;
    int half = (b >= HOP_HB) ? 1 : 0;
    int orig = b - half * HOP_HB;
    // bijective XCD chunk swizzle within half: nwg=12500, q=1562, r=4 (m204 form)
    int xcd = orig & 7;
    int idx = orig >> 3;
    int cbase = (xcd < 4) ? xcd * 1563 : 4 * 1563 + (xcd - 4) * 1562;
    int wg = cbase + idx;

    int lane = threadIdx.x & 63;
    int g = lane >> 2;                 // 16 edge groups
    int q = lane & 3;                  // 4 x 16B = 64B half-row
    int t = __builtin_amdgcn_readfirstlane(wg * 4 + (threadIdx.x >> 6));
    if (t >= N_NODES) return;
    int deg = fill8[t];
    const uint4v* hp = hin + (size_t)half * ZPL;

    float acc[8] = {};
    if (g == 0) {                      // self-loop (weight 1)
        uint4v r = hp[t * 4 + q];
        const unsigned int rw[4] = { r.x, r.y, r.z, r.w };
        #pragma unroll
        for (int j = 0; j < 4; ++j) {
            acc[2 * j]     = __uint_as_float(rw[j] << 16);
            acc[2 * j + 1] = __uint_as_float(rw[j] & 0xffff0000u);
        }
    }
    for (int base = 0; base < deg; base += 16) {
        int e = base + g;
        if (e < deg) {
            int s = (int)esrc[(size_t)e * N_NODES + t];
            uint4v r = hp[s * 4 + q];
            const unsigned int rw[4] = { r.x, r.y, r.z, r.w };
            #pragma unroll
            for (int j = 0; j < 4; ++j) {
                acc[2 * j]     += __uint_as_float(rw[j] << 16);
                acc[2 * j + 1] += __uint_as_float(rw[j] & 0xffff0000u);
            }
        }
    }
    #pragma unroll
    for (int j = 0; j < 8; ++j) {      // reduce across 16 groups
        acc[j] += __shfl_xor(acc[j], 4);
        acc[j] += __shfl_xor(acc[j], 8);
        acc[j] += __shfl_xor(acc[j], 16);
        acc[j] += __shfl_xor(acc[j], 32);
    }
    if (g == 0) {
        if (!last) {                   // z1 = u1 / (deg+1), bf16, planar half
            float rdeg = 1.0f / (float)(deg + 1);
            uint4v pk;
            pk.x = bpack(acc[0] * rdeg, acc[1] * rdeg);
            pk.y = bpack(acc[2] * rdeg, acc[3] * rdeg);
            pk.z = bpack(acc[4] * rdeg, acc[5] * rdeg);
            pk.w = bpack(acc[6] * rdeg, acc[7] * rdeg);
            __builtin_nontemporal_store(pk,
                (uint4v*)hout + (size_t)half * ZPL + t * 4 + q);
        } else {                       // out = dinv*u2 + b, fp32 interleaved
            float d = rsqrtf((float)(deg + 1));
            float4 b0 = ((const float4*)bias)[half * 8 + q * 2];
            float4 b1 = ((const float4*)bias)[half * 8 + q * 2 + 1];
            float4v o0 = { d * acc[0] + b0.x, d * acc[1] + b0.y,
                           d * acc[2] + b0.z, d * acc[3] + b0.w };
            float4v o1 = { d * acc[4] + b1.x, d * acc[5] + b1.y,
                           d * acc[6] + b1.z, d * acc[7] + b1.w };
            __builtin_nontemporal_store(o0, (float4v*)hout + t * 16 + half * 8 + q * 2);
            __builtin_nontemporal_store(o1, (float4v*)hout + t * 16 + half * 8 + q * 2 + 1);
        }
    }
}

// =================== launch ===================
extern "C" void kernel_launch(void* const* d_in, const int* in_sizes, int n_in,
                              void* d_out, int out_size, void* d_ws, size_t ws_size,
                              hipStream_t stream) {
    const float* x  = (const float*)d_in[0];
    const int*   ei = (const int*)d_in[1];
    const float* W  = (const float*)d_in[2];
    const float* b  = (const float*)d_in[3];
    float*       out = (float*)d_out;

    const int* row = ei;
    const int* col = ei + N_EDGES;

    // ws (~30 MB): gcur | binbuf | esrc | fill8 | y | z0 | z1
    char* ws = (char*)d_ws;
    size_t a = 0;
    auto alloc = [&](size_t bytes) { char* p = ws + a; a = (a + bytes + 255) & ~(size_t)255; return p; };
    int*            gcur   = (int*)           alloc(NBINS * sizeof(int));
    unsigned int*   binbuf = (unsigned int*)  alloc((size_t)NBINS * BINCAP * 4);
    unsigned short* esrc   = (unsigned short*)alloc((size_t)PCAP * N_NODES * 2);
    unsigned char*  fill8  = (unsigned char*) alloc(N_NODES);
    float*          y      = (float*)         alloc((size_t)N_NODES * OUT_CH * 4);
    unsigned int*   z0     = (unsigned int*)  alloc((size_t)N_NODES * OUT_CH * 2);
    unsigned int*   z1     = (unsigned int*)  alloc((size_t)N_NODES * OUT_CH * 2);

    hipMemsetAsync(gcur, 0, NBINS * sizeof(int), stream);

    const int B = 256;
    int gS = (N_NODES * 8 + B - 1) / B;   // 1563
    int gH = 2 * HOP_HB;                  // 25000 (two half-channel passes)

    scatter_a<<<SA_B, B, 0, stream>>>(row, col, binbuf, gcur);
    scatb_gemm<<<SB_B + GEMM_BL, 1024, 0, stream>>>(binbuf, gcur, esrc, fill8, x, W, y);
    scale_z0 <<<gS, B, 0, stream>>>(y, fill8, (uint4v*)z0);
    hop_gather<<<gH, B, 0, stream>>>((const uint4v*)z0, (void*)z1, fill8, esrc, b, 0);
    hop_gather<<<gH, B, 0, stream>>>((const uint4v*)z1, (void*)out, fill8, esrc, b, 1);
}

// Round 3
// 149.980 us; speedup vs baseline: 1.2815x; 1.2815x over previous
//
#include <hip/hip_runtime.h>

#define N_NODES 50000
#define IN_CH   128
#define OUT_CH  64
#define N_EDGES 800000
#define NBINS   49      // bin = t >> 10
#define LBCAP   128     // per-(block,bin) LDS cap; Poisson(32.7), P(>128)~0
#define BINCAP  20000   // per-bin global cap; mean 16.3K, sd 128
#define PCAP    64      // esrc planes; deg Poisson(16), P(>64)~1e-18
#define WT_STR  136     // bf16 per WT row
#define SA_B    500     // scatter_a blocks (2/CU); 500*1600 = 800000 exactly
#define SA_E    1600
#define SB_B    49      // scatter_b blocks (single-writer per bin)
#define GEMM_BL 196     // gemm blocks in fused K2; 196*16 waves >= 3125 tiles
#define HOP_NB  782     // hop blocks per half: 782*64 = 50048 >= 50000
#define ZPL     (N_NODES * 4)   // uint4 per z plane (half-channels, 64B/node)

// NOTE (R9): ~92us of dur_us is harness 256MB ws poison fills. Budget = dur-92.
// NOTE (R1): integer inputs arrive as int32.
// NOTE (R12-R14): random fine-grain global stores -> ~50MB partial-line traffic;
// two-phase binning fixes writes; phases must run dense + overlap the gemm.
// NOTE (R15/R17): planar half-channel z (two 3.2MB planes) makes gathers
// L2-resident: hop FETCH 100MB->27MB confirmed. BUT R17's 4-lane/node,
// 1-node/wave structure paid 100K waves of prologue + a 32-op shfl reduce
// tree (3.2M DS ops ~ 25us) -> hop got SLOWER (44us, VALUBusy 35%, hbm 11%).
// NOTE (R18): reduce-free hop: wave = 16 nodes x 4 lanes x 16B (one L2 line
// per node-edge gather), sequential edge loop per node, NO shuffles, 6.3K
// waves. half = blockIdx&1 pins each plane to an XCD parity class under
// round-robin dispatch.
// NOTE (R16): __builtin_nontemporal_store needs ext_vector types (uint4v).

using short8  = __attribute__((ext_vector_type(8))) short;
using float4v = __attribute__((ext_vector_type(4))) float;
using uint4v  = __attribute__((ext_vector_type(4))) unsigned int;

__device__ __forceinline__ unsigned int bpack(float a, float b) {
    unsigned int ua = __float_as_uint(a), ub = __float_as_uint(b);
    unsigned int ra = (ua + 0x7fffu + ((ua >> 16) & 1u)) >> 16;
    unsigned int rb = (ub + 0x7fffu + ((ub >> 16) & 1u)) & 0xffff0000u;
    return (ra & 0xffffu) | rb;
}

// =================== K1: scatter phase A — bin edges, dense append ===================
__global__ __launch_bounds__(256) void scatter_a(const int* __restrict__ row,
        const int* __restrict__ col, unsigned int* __restrict__ binbuf,
        int* __restrict__ gcur) {
    __shared__ unsigned int sbuf[NBINS][LBCAP];   // 25 KB
    __shared__ int scnt[NBINS];
    __shared__ int sdst[NBINS];
    const int tid = threadIdx.x;
    if (tid < NBINS) scnt[tid] = 0;
    __syncthreads();
    const int e0 = blockIdx.x * SA_E;
    for (int i = tid; i < SA_E / 4; i += 256) {      // 400 int4 per block
        int e = e0 + i * 4;
        int4 t4 = *(const int4*)&col[e];
        int4 s4 = *(const int4*)&row[e];
        const int ts[4] = { t4.x, t4.y, t4.z, t4.w };
        const int ss[4] = { s4.x, s4.y, s4.z, s4.w };
        #pragma unroll
        for (int j = 0; j < 4; ++j) {
            int b = ts[j] >> 10;
            int pos = atomicAdd(&scnt[b], 1);        // LDS atomic
            if (pos < LBCAP)
                sbuf[b][pos] = ((unsigned)(ts[j] & 1023) << 16) | (unsigned)ss[j];
        }
    }
    __syncthreads();
    if (tid < NBINS) {
        int c = scnt[tid]; if (c > LBCAP) c = LBCAP; scnt[tid] = c;
        sdst[tid] = atomicAdd(&gcur[tid], c);        // 1 global atomic/bin
    }
    __syncthreads();
    const int wave = tid >> 6, lane = tid & 63;
    for (int b = wave; b < NBINS; b += 4) {          // wave-parallel dense copy
        int c = scnt[b];
        size_t d = (size_t)b * BINCAP + sdst[b];
        for (int i = lane; i < c; i += 64)
            binbuf[d + i] = sbuf[b][i];
    }
}

// =================== K2 (fused): scatter_b (blocks [0,49)) || MFMA gemm ===================
__global__ __launch_bounds__(1024) void scatb_gemm(
        const unsigned int* __restrict__ binbuf, const int* __restrict__ gcur,
        unsigned short* __restrict__ esrc, unsigned char* __restrict__ fill8,
        const float* __restrict__ x, const float* __restrict__ W,
        float* __restrict__ y) {
    const int bid = blockIdx.x, tid = threadIdx.x;
    if (bid < SB_B) {   // ---- scatter_b ----
        __shared__ int lcnt[1024];
        const int t0 = bid << 10;
        lcnt[tid] = 0;
        __syncthreads();
        int cnt = gcur[bid]; if (cnt > BINCAP) cnt = BINCAP;
        const unsigned int* src = binbuf + (size_t)bid * BINCAP;
        for (int i = tid; i < cnt; i += 1024) {
            unsigned int e = src[i];                 // dense read
            int tl = e >> 16;
            int pos = atomicAdd(&lcnt[tl], 1);       // LDS atomic
            int t = t0 + tl;
            if (pos < PCAP && t < N_NODES)
                esrc[(size_t)pos * N_NODES + t] = (unsigned short)(e & 0xffffu);
        }
        __syncthreads();
        int t = t0 + tid;
        if (t < N_NODES) {
            int v = lcnt[tid]; if (v > PCAP) v = PCAP;
            fill8[t] = (unsigned char)v;
        }
        return;
    }
    // ---- gemm ----
    __shared__ unsigned short sWT[64 * WT_STR];      // 17.4 KB, bf16 WT[c][k]
    for (int i = tid; i < IN_CH * OUT_CH; i += 1024) {
        int k = i >> 6, c = i & 63;
        unsigned int u = __float_as_uint(W[i]);
        u = (u + 0x7fffu + ((u >> 16) & 1u)) >> 16;  // RNE to bf16
        sWT[c * WT_STR + k] = (unsigned short)u;
    }
    __syncthreads();
    const int lane = tid & 63;
    const int quad = lane >> 4;
    const int c15  = lane & 15;
    const int tile = (bid - SB_B) * 16 + (tid >> 6); // one tile per wave
    if (tile >= N_NODES / 16) return;                // after the only barrier

    short8 bf[4][4];
    #pragma unroll
    for (int t = 0; t < 4; ++t)
        #pragma unroll
        for (int ch = 0; ch < 4; ++ch)
            bf[ch][t] = *(const short8*)&sWT[(t * 16 + c15) * WT_STR + ch * 32 + quad * 8];

    const float* xr = x + ((size_t)tile * 16 + c15) * IN_CH;
    float4v acc[4] = {{0.f,0.f,0.f,0.f},{0.f,0.f,0.f,0.f},
                      {0.f,0.f,0.f,0.f},{0.f,0.f,0.f,0.f}};
    #pragma unroll
    for (int ch = 0; ch < 4; ++ch) {
        float4 f0 = *(const float4*)(xr + ch * 32 + quad * 8);
        float4 f1 = *(const float4*)(xr + ch * 32 + quad * 8 + 4);
        unsigned int d0 = bpack(f0.x, f0.y), d1 = bpack(f0.z, f0.w);
        unsigned int d2 = bpack(f1.x, f1.y), d3 = bpack(f1.z, f1.w);
        short8 a8;
        a8[0] = (short)d0; a8[1] = (short)(d0 >> 16);
        a8[2] = (short)d1; a8[3] = (short)(d1 >> 16);
        a8[4] = (short)d2; a8[5] = (short)(d2 >> 16);
        a8[6] = (short)d3; a8[7] = (short)(d3 >> 16);
        #pragma unroll
        for (int t = 0; t < 4; ++t)
            acc[t] = __builtin_amdgcn_mfma_f32_16x16x32_bf16(a8, bf[ch][t], acc[t], 0, 0, 0);
    }
    #pragma unroll
    for (int t = 0; t < 4; ++t)
        #pragma unroll
        for (int r = 0; r < 4; ++r)
            y[((size_t)tile * 16 + quad * 4 + r) * OUT_CH + t * 16 + c15] = acc[t][r];
}

// =================== K3: z0 = D^-1/2 y (fp32 -> bf16, PLANAR halves) ===================
__global__ __launch_bounds__(256) void scale_z0(const float* __restrict__ y,
        const unsigned char* __restrict__ fill8, uint4v* __restrict__ z0) {
    int gid = blockIdx.x * 256 + threadIdx.x;
    if (gid >= N_NODES * 8) return;
    int n = gid >> 3, q = gid & 7;
    int half = q >> 2, qq = q & 3;
    float d = rsqrtf((float)((int)fill8[n] + 1));
    float4 a = ((const float4*)y)[n * 16 + q * 2];
    float4 b = ((const float4*)y)[n * 16 + q * 2 + 1];
    uint4v pk;
    pk.x = bpack(d * a.x, d * a.y);
    pk.y = bpack(d * a.z, d * a.w);
    pk.z = bpack(d * b.x, d * b.y);
    pk.w = bpack(d * b.z, d * b.w);
    z0[(size_t)half * ZPL + n * 4 + qq] = pk;
}

// =================== K4/K5: reduce-free (A+I) gather, half-channel passes ===================
// Wave = 16 nodes x 4 lanes x 16B (one 64B half-row = one L2 line per gather).
// Sequential edge loop per node; NO cross-lane reduce, NO LDS.
// half = blockIdx&1 -> each XCD parity class touches only one 3.2MB plane.
__global__ __launch_bounds__(256) void hop_gather(const uint4v* __restrict__ hin,
        void* __restrict__ hout, const unsigned char* __restrict__ fill8,
        const unsigned short* __restrict__ esrc, const float* __restrict__ bias,
        int last) {
    const int half = blockIdx.x & 1;
    const int wg   = blockIdx.x >> 1;
    const int lane = threadIdx.x & 63;
    const int r    = lane >> 2;        // node within wave [0,16)
    const int q    = lane & 3;         // 16B quarter of the 64B half-row
    const int t    = wg * 64 + (threadIdx.x >> 6) * 16 + r;
    if (t >= N_NODES) return;
    const int deg = fill8[t];
    const uint4v* hp = hin + (size_t)half * ZPL;

    // self-loop (weight 1)
    uint4v rr = hp[t * 4 + q];
    float acc[8];
    {
        const unsigned int rw[4] = { rr.x, rr.y, rr.z, rr.w };
        #pragma unroll
        for (int j = 0; j < 4; ++j) {
            acc[2 * j]     = __uint_as_float(rw[j] << 16);
            acc[2 * j + 1] = __uint_as_float(rw[j] & 0xffff0000u);
        }
    }
    // sequential edges, 1-deep esrc prefetch
    int e = 0;
    int s = (0 < deg) ? (int)esrc[t] : -1;
    while (__any(s >= 0)) {
        int sn = (e + 1 < deg) ? (int)esrc[(size_t)(e + 1) * N_NODES + t] : -1;
        if (s >= 0) {
            uint4v v = hp[s * 4 + q];
            const unsigned int rw[4] = { v.x, v.y, v.z, v.w };
            #pragma unroll
            for (int j = 0; j < 4; ++j) {
                acc[2 * j]     += __uint_as_float(rw[j] << 16);
                acc[2 * j + 1] += __uint_as_float(rw[j] & 0xffff0000u);
            }
        }
        s = sn; ++e;
    }

    if (!last) {                       // z1 = u1 / (deg+1), bf16, planar half
        float rdeg = 1.0f / (float)(deg + 1);
        uint4v pk;
        pk.x = bpack(acc[0] * rdeg, acc[1] * rdeg);
        pk.y = bpack(acc[2] * rdeg, acc[3] * rdeg);
        pk.z = bpack(acc[4] * rdeg, acc[5] * rdeg);
        pk.w = bpack(acc[6] * rdeg, acc[7] * rdeg);
        __builtin_nontemporal_store(pk,
            (uint4v*)hout + (size_t)half * ZPL + t * 4 + q);
    } else {                           // out = dinv*u2 + b, fp32 interleaved
        float d = rsqrtf((float)(deg + 1));
        float4 b0 = ((const float4*)bias)[half * 8 + q * 2];
        float4 b1 = ((const float4*)bias)[half * 8 + q * 2 + 1];
        float4v o0 = { d * acc[0] + b0.x, d * acc[1] + b0.y,
                       d * acc[2] + b0.z, d * acc[3] + b0.w };
        float4v o1 = { d * acc[4] + b1.x, d * acc[5] + b1.y,
                       d * acc[6] + b1.z, d * acc[7] + b1.w };
        __builtin_nontemporal_store(o0, (float4v*)hout + t * 16 + half * 8 + q * 2);
        __builtin_nontemporal_store(o1, (float4v*)hout + t * 16 + half * 8 + q * 2 + 1);
    }
}

// =================== launch ===================
extern "C" void kernel_launch(void* const* d_in, const int* in_sizes, int n_in,
                              void* d_out, int out_size, void* d_ws, size_t ws_size,
                              hipStream_t stream) {
    const float* x  = (const float*)d_in[0];
    const int*   ei = (const int*)d_in[1];
    const float* W  = (const float*)d_in[2];
    const float* b  = (const float*)d_in[3];
    float*       out = (float*)d_out;

    const int* row = ei;
    const int* col = ei + N_EDGES;

    // ws (~30 MB): gcur | binbuf | esrc | fill8 | y | z0 | z1
    char* ws = (char*)d_ws;
    size_t a = 0;
    auto alloc = [&](size_t bytes) { char* p = ws + a; a = (a + bytes + 255) & ~(size_t)255; return p; };
    int*            gcur   = (int*)           alloc(NBINS * sizeof(int));
    unsigned int*   binbuf = (unsigned int*)  alloc((size_t)NBINS * BINCAP * 4);
    unsigned short* esrc   = (unsigned short*)alloc((size_t)PCAP * N_NODES * 2);
    unsigned char*  fill8  = (unsigned char*) alloc(N_NODES);
    float*          y      = (float*)         alloc((size_t)N_NODES * OUT_CH * 4);
    unsigned int*   z0     = (unsigned int*)  alloc((size_t)N_NODES * OUT_CH * 2);
    unsigned int*   z1     = (unsigned int*)  alloc((size_t)N_NODES * OUT_CH * 2);

    hipMemsetAsync(gcur, 0, NBINS * sizeof(int), stream);

    const int B = 256;
    int gS = (N_NODES * 8 + B - 1) / B;   // 1563
    int gH = 2 * HOP_NB;                  // 1564 (two interleaved half passes)

    scatter_a<<<SA_B, B, 0, stream>>>(row, col, binbuf, gcur);
    scatb_gemm<<<SB_B + GEMM_BL, 1024, 0, stream>>>(binbuf, gcur, esrc, fill8, x, W, y);
    scale_z0 <<<gS, B, 0, stream>>>(y, fill8, (uint4v*)z0);
    hop_gather<<<gH, B, 0, stream>>>((const uint4v*)z0, (void*)z1, fill8, esrc, b, 0);
    hop_gather<<<gH, B, 0, stream>>>((const uint4v*)z1, (void*)out, fill8, esrc, b, 1);
}